// Round 3
// baseline (1035.441 us; speedup 1.0000x reference)
//
#include <hip/hip_runtime.h>
#include <math.h>

#define QL 2048
#define SL 2048
#define BS 4
#define NH 4
// per-half projected tensor size in floats: bs*L*128
#define FSZ ((size_t)BS * QL * 128)   // 1,048,576

// ---------------------------------------------------------------------------
// Projection GEMM: Y[M=8192][128] = X[M][256] @ W[256][128]
// grid: (128 m-tiles, 2 n-tiles, 6 gemms); block 256; C-tile 64x64, 4x4/thread
// ---------------------------------------------------------------------------
__global__ __launch_bounds__(256) void proj_gemm(
    const float* __restrict__ q, const float* __restrict__ k, const float* __restrict__ v,
    const float* __restrict__ Wqa, const float* __restrict__ Wqb,
    const float* __restrict__ Wka, const float* __restrict__ Wkb,
    const float* __restrict__ Wva, const float* __restrict__ Wvb,
    float* __restrict__ ws)
{
    int id = blockIdx.z;
    const float* X; const float* W;
    const size_t HALF = (size_t)BS * QL * 256;
    switch (id) {
      case 0: X = q;        W = Wqa; break;
      case 1: X = q + HALF; W = Wqb; break;
      case 2: X = k;        W = Wka; break;
      case 3: X = k + HALF; W = Wkb; break;
      case 4: X = v;        W = Wva; break;
      default:X = v + HALF; W = Wvb; break;
    }
    float* Y = ws + (size_t)id * FSZ;
    int m0 = blockIdx.x * 64;
    int n0 = blockIdx.y * 64;
    __shared__ float At[64][68];
    __shared__ float Bt[64][68];
    int t = threadIdx.x;
    int tx = t & 15, ty = t >> 4;
    float acc[4][4] = {};
    for (int kc = 0; kc < 256; kc += 64) {
        for (int f = t; f < 1024; f += 256) {
            int row = f >> 4, c4 = (f & 15) * 4;
            *(float4*)&At[row][c4] = *(const float4*)(X + (size_t)(m0 + row) * 256 + kc + c4);
        }
        for (int f = t; f < 1024; f += 256) {
            int row = f >> 4, c4 = (f & 15) * 4;
            *(float4*)&Bt[row][c4] = *(const float4*)(W + (size_t)(kc + row) * 128 + n0 + c4);
        }
        __syncthreads();
        for (int j = 0; j < 64; j += 4) {
            float4 a4[4], b4[4];
            #pragma unroll
            for (int i = 0; i < 4; i++) a4[i] = *(const float4*)&At[ty * 4 + i][j];
            #pragma unroll
            for (int jj = 0; jj < 4; jj++) b4[jj] = *(const float4*)&Bt[j + jj][tx * 4];
            #pragma unroll
            for (int i = 0; i < 4; i++) {
                #pragma unroll
                for (int jj = 0; jj < 4; jj++) {
                    float av = ((const float*)&a4[i])[jj];
                    acc[i][0] += av * b4[jj].x;
                    acc[i][1] += av * b4[jj].y;
                    acc[i][2] += av * b4[jj].z;
                    acc[i][3] += av * b4[jj].w;
                }
            }
        }
        __syncthreads();
    }
    for (int i = 0; i < 4; i++) {
        float4 o = make_float4(acc[i][0], acc[i][1], acc[i][2], acc[i][3]);
        *(float4*)(Y + (size_t)(m0 + ty * 4 + i) * 128 + n0 + tx * 4) = o;
    }
}

// ---------------------------------------------------------------------------
// Spatial rotation: out[b,h,t,i] = sum_j E[i,j] * head(h)[j]
// head(h) = [ ha[(h&1)*64 + 0:64], hb[(h>>1)*64 + 0:64] ]
// One block per token. per_token selects E indexing (q: per-b, kv: per-(b,s)).
// ---------------------------------------------------------------------------
__global__ __launch_bounds__(256) void rot_kernel(
    const float* __restrict__ ha, const float* __restrict__ hb,
    const float* __restrict__ E0, int per_token,
    float* __restrict__ outp)
{
    int tkn = blockIdx.x;
    int b = blockIdx.y;
    const float* E = E0 + (per_token ? ((size_t)(b * SL + tkn) * 16384)
                                     : ((size_t)b * 16384));
    __shared__ float hv[4][128];
    __shared__ float outl[4][128];
    int tid = threadIdx.x;
    size_t tok = (size_t)(b * QL + tkn) * 128;
    for (int idx = tid; idx < 512; idx += 256) {
        int h = idx >> 7, d = idx & 127;
        float val = (d < 64) ? ha[tok + (h & 1) * 64 + d]
                             : hb[tok + (h >> 1) * 64 + (d - 64)];
        hv[h][d] = val;
    }
    __syncthreads();
    int w = tid >> 6, lane = tid & 63;
    int half = lane >> 5, l5 = lane & 31;
    for (int it = 0; it < 16; ++it) {
        int i = w * 32 + it * 2 + half;
        float4 e = *(const float4*)(E + (size_t)i * 128 + l5 * 4);
        float acc[4];
        #pragma unroll
        for (int h = 0; h < 4; h++) {
            float4 x = *(const float4*)&hv[h][l5 * 4];
            acc[h] = e.x * x.x + e.y * x.y + e.z * x.z + e.w * x.w;
        }
        #pragma unroll
        for (int off = 1; off < 32; off <<= 1) {
            #pragma unroll
            for (int h = 0; h < 4; h++) acc[h] += __shfl_xor(acc[h], off);
        }
        if (l5 < 4) outl[l5][i] = acc[l5];
    }
    __syncthreads();
    for (int idx = tid; idx < 512; idx += 256) {
        int h = idx >> 7, d = idx & 127;
        outp[((size_t)(b * NH + h) * QL + tkn) * 128 + d] = outl[h][d];
    }
}

// ---------------------------------------------------------------------------
// Score GEMM: S[bh,q,s] = qrot[bh,q,:]·krot[bh,s,:] * scale - 1e9*mask - bias
// C-tile 64x64, K=128 (one shot), XCD-chunked swizzle for L2 locality.
// ---------------------------------------------------------------------------
__global__ __launch_bounds__(256) void score_kernel(
    const float* __restrict__ qrot, const float* __restrict__ krot,
    const float* __restrict__ bias, const int* __restrict__ mask,
    float* __restrict__ attn)
{
    int nwg = gridDim.x;                 // 16384
    int bid = blockIdx.x;
    int cpx = nwg >> 3;
    int wg = (bid & 7) * cpx + (bid >> 3);
    int bh = wg >> 10;
    int rem = wg & 1023;
    int qt = rem >> 5, st = rem & 31;
    int q0 = qt * 64, s0 = st * 64;
    int b = bh >> 2;
    const float* A = qrot + (size_t)bh * QL * 128;
    const float* B = krot + (size_t)bh * SL * 128;
    __shared__ float Aq[64][132];
    __shared__ float Bk[64][132];
    int t = threadIdx.x;
    for (int f = t; f < 2048; f += 256) {
        int row = f >> 5, c4 = (f & 31) * 4;
        *(float4*)&Aq[row][c4] = *(const float4*)(A + (size_t)(q0 + row) * 128 + c4);
        *(float4*)&Bk[row][c4] = *(const float4*)(B + (size_t)(s0 + row) * 128 + c4);
    }
    __syncthreads();
    int tx = t & 15, ty = t >> 4;
    int r0 = ty * 4, c0 = tx * 4;
    float acc[4][4] = {};
    for (int j = 0; j < 128; j += 4) {
        float4 a4[4], b4[4];
        #pragma unroll
        for (int i = 0; i < 4; i++) a4[i] = *(const float4*)&Aq[r0 + i][j];
        #pragma unroll
        for (int c = 0; c < 4; c++) b4[c] = *(const float4*)&Bk[c0 + c][j];
        #pragma unroll
        for (int i = 0; i < 4; i++) {
            #pragma unroll
            for (int c = 0; c < 4; c++) {
                acc[i][c] += a4[i].x * b4[c].x + a4[i].y * b4[c].y
                           + a4[i].z * b4[c].z + a4[i].w * b4[c].w;
            }
        }
    }
    const float scale = 0.08838834764831845f;   // 1/sqrt(128)
    float adj[4];
    #pragma unroll
    for (int c = 0; c < 4; c++) {
        int s = s0 + c0 + c;
        adj[c] = -1e9f * (float)mask[b * SL + s] - bias[b * SL + s];
    }
    for (int i = 0; i < 4; i++) {
        float4 o = make_float4(acc[i][0] * scale + adj[0],
                               acc[i][1] * scale + adj[1],
                               acc[i][2] * scale + adj[2],
                               acc[i][3] * scale + adj[3]);
        *(float4*)(attn + ((size_t)bh * QL + q0 + r0 + i) * SL + s0 + c0) = o;
    }
}

// ---------------------------------------------------------------------------
// Row softmax over the 2048-wide score rows, in place in d_out's attn region.
// 2 rows per block.
// ---------------------------------------------------------------------------
__global__ __launch_bounds__(256) void softmax_kernel(float* __restrict__ attn)
{
    int blk = blockIdx.x;                       // 16384 blocks, 2 rows each
    size_t rowbase = (size_t)blk * 2 * SL;
    __shared__ float rowe[2][2048];
    __shared__ float redM[2][2];
    __shared__ float redS[2][2];
    __shared__ float linv[2];
    int t = threadIdx.x;
    for (int f = t; f < 1024; f += 256) {
        int r = f >> 9, c4 = (f & 511) * 4;
        *(float4*)&rowe[r][c4] = *(const float4*)(attn + rowbase + (size_t)r * SL + c4);
    }
    __syncthreads();
    int r = t >> 7, tr = t & 127;
    float m = -INFINITY;
    for (int kk = 0; kk < 16; ++kk) m = fmaxf(m, rowe[r][tr + 128 * kk]);
    #pragma unroll
    for (int off = 1; off < 64; off <<= 1) m = fmaxf(m, __shfl_xor(m, off));
    if ((t & 63) == 0) redM[r][(t >> 6) & 1] = m;
    __syncthreads();
    m = fmaxf(redM[r][0], redM[r][1]);
    float s = 0.f;
    for (int kk = 0; kk < 16; ++kk) {
        float e = __expf(rowe[r][tr + 128 * kk] - m);
        rowe[r][tr + 128 * kk] = e;
        s += e;
    }
    #pragma unroll
    for (int off = 1; off < 64; off <<= 1) s += __shfl_xor(s, off);
    if ((t & 63) == 0) redS[r][(t >> 6) & 1] = s;
    __syncthreads();                            // also fences rowe exp-writes
    if (t < 2) linv[t] = 1.0f / (redS[t][0] + redS[t][1]);
    __syncthreads();
    for (int f = t; f < 1024; f += 256) {
        int rr = f >> 9, c4 = (f & 511) * 4;
        float4 e4 = *(const float4*)&rowe[rr][c4];
        float iv = linv[rr];
        e4.x *= iv; e4.y *= iv; e4.z *= iv; e4.w *= iv;
        *(float4*)(attn + rowbase + (size_t)rr * SL + c4) = e4;
    }
}

// ---------------------------------------------------------------------------
// PV GEMM: outh[bh,q,d] = sum_s attn[bh,q,s] * vh[b,h,s,d]
// vh assembled on the fly from va/vb. C-tile 64x128, 4x8/thread.
// ---------------------------------------------------------------------------
__global__ __launch_bounds__(256) void pv_kernel(
    const float* __restrict__ attn, const float* __restrict__ va, const float* __restrict__ vb,
    float* __restrict__ outh)
{
    int bid = blockIdx.x;                 // 512 = 16 bh * 32 q-tiles
    int bh = bid >> 5, qt = bid & 31;
    int b = bh >> 2, h = bh & 3;
    int q0 = qt * 64;
    __shared__ float At[64][68];
    __shared__ float Bt[64][132];
    int t = threadIdx.x;
    int tx = t & 15, ty = t >> 4;
    float acc[4][8] = {};
    int hao = (h & 1) * 64, hbo = (h >> 1) * 64;
    for (int s0 = 0; s0 < SL; s0 += 64) {
        for (int f = t; f < 1024; f += 256) {
            int row = f >> 4, c4 = (f & 15) * 4;
            *(float4*)&At[row][c4] =
                *(const float4*)(attn + ((size_t)bh * QL + q0 + row) * SL + s0 + c4);
        }
        for (int f = t; f < 2048; f += 256) {
            int row = f >> 5, c4 = (f & 31) * 4;
            size_t tokoff = (size_t)(b * SL + s0 + row) * 128;
            float4 vv = (c4 < 64) ? *(const float4*)(va + tokoff + hao + c4)
                                  : *(const float4*)(vb + tokoff + hbo + (c4 - 64));
            *(float4*)&Bt[row][c4] = vv;
        }
        __syncthreads();
        for (int j = 0; j < 64; j += 4) {
            float4 a4[4];
            #pragma unroll
            for (int i = 0; i < 4; i++) a4[i] = *(const float4*)&At[ty * 4 + i][j];
            #pragma unroll
            for (int jj = 0; jj < 4; jj++) {
                float4 blo = *(const float4*)&Bt[j + jj][tx * 8];
                float4 bhi = *(const float4*)&Bt[j + jj][tx * 8 + 4];
                #pragma unroll
                for (int i = 0; i < 4; i++) {
                    float av = ((const float*)&a4[i])[jj];
                    acc[i][0] += av * blo.x; acc[i][1] += av * blo.y;
                    acc[i][2] += av * blo.z; acc[i][3] += av * blo.w;
                    acc[i][4] += av * bhi.x; acc[i][5] += av * bhi.y;
                    acc[i][6] += av * bhi.z; acc[i][7] += av * bhi.w;
                }
            }
        }
        __syncthreads();
    }
    for (int i = 0; i < 4; i++) {
        float4 o1 = make_float4(acc[i][0], acc[i][1], acc[i][2], acc[i][3]);
        float4 o2 = make_float4(acc[i][4], acc[i][5], acc[i][6], acc[i][7]);
        size_t base = ((size_t)bh * QL + q0 + ty * 4 + i) * 128 + tx * 8;
        *(float4*)(outh + base) = o1;
        *(float4*)(outh + base + 4) = o2;
    }
}

// ---------------------------------------------------------------------------
// Output projection: oa/ob[b,t,o] = sum_{h,d} outh[b,h,t,(sel?64:0)+d] * W[h*64+d][o]
// ---------------------------------------------------------------------------
__global__ __launch_bounds__(256) void oproj_kernel(
    const float* __restrict__ outh, const float* __restrict__ Woa, const float* __restrict__ Wob,
    float* __restrict__ outp)
{
    int bid = blockIdx.x;                 // 1024 = 2 sel * 4 b * 32 t-tiles * 4 o-tiles
    int sel = bid >> 9;
    int rem = bid & 511;
    int b = rem >> 7;
    int rem2 = rem & 127;
    int tt = rem2 >> 2, ot = rem2 & 3;
    int t0 = tt * 64, o0 = ot * 64;
    const float* W = sel ? Wob : Woa;
    int doff = sel ? 64 : 0;
    __shared__ float At[64][68];
    __shared__ float Bt[64][68];
    int t = threadIdx.x;
    int tx = t & 15, ty = t >> 4;
    float acc[4][4] = {};
    for (int kc = 0; kc < 256; kc += 64) {
        int h = kc >> 6;
        for (int f = t; f < 1024; f += 256) {
            int row = f >> 4, c4 = (f & 15) * 4;
            *(float4*)&At[row][c4] =
                *(const float4*)(outh + ((size_t)(b * NH + h) * QL + t0 + row) * 128 + doff + c4);
        }
        for (int f = t; f < 1024; f += 256) {
            int row = f >> 4, c4 = (f & 15) * 4;
            *(float4*)&Bt[row][c4] = *(const float4*)(W + (size_t)(kc + row) * 256 + o0 + c4);
        }
        __syncthreads();
        for (int j = 0; j < 64; j += 4) {
            float4 a4[4], b4[4];
            #pragma unroll
            for (int i = 0; i < 4; i++) a4[i] = *(const float4*)&At[ty * 4 + i][j];
            #pragma unroll
            for (int jj = 0; jj < 4; jj++) b4[jj] = *(const float4*)&Bt[j + jj][tx * 4];
            #pragma unroll
            for (int i = 0; i < 4; i++) {
                #pragma unroll
                for (int jj = 0; jj < 4; jj++) {
                    float av = ((const float*)&a4[i])[jj];
                    acc[i][0] += av * b4[jj].x;
                    acc[i][1] += av * b4[jj].y;
                    acc[i][2] += av * b4[jj].z;
                    acc[i][3] += av * b4[jj].w;
                }
            }
        }
        __syncthreads();
    }
    for (int i = 0; i < 4; i++) {
        float4 o = make_float4(acc[i][0], acc[i][1], acc[i][2], acc[i][3]);
        *(float4*)(outp + ((size_t)((sel * BS + b) * QL) + t0 + ty * 4 + i) * 256 + o0 + tx * 4) = o;
    }
}

extern "C" void kernel_launch(void* const* d_in, const int* in_sizes, int n_in,
                              void* d_out, int out_size, void* d_ws, size_t ws_size,
                              hipStream_t stream)
{
    const float* q    = (const float*)d_in[0];
    const float* k    = (const float*)d_in[1];
    const float* v    = (const float*)d_in[2];
    const float* qse  = (const float*)d_in[3];
    const float* kvse = (const float*)d_in[4];
    const float* bias = (const float*)d_in[5];
    const int*   mask = (const int*)d_in[6];
    const float* Wqa  = (const float*)d_in[7];
    const float* Wqb  = (const float*)d_in[8];
    const float* Wka  = (const float*)d_in[9];
    const float* Wkb  = (const float*)d_in[10];
    const float* Wva  = (const float*)d_in[11];
    const float* Wvb  = (const float*)d_in[12];
    const float* Woa  = (const float*)d_in[13];
    const float* Wob  = (const float*)d_in[14];

    float* outp = (float*)d_out;
    float* attn = outp + (size_t)2 * BS * QL * 256;   // attn region of d_out

    float* ws   = (float*)d_ws;
    float* qa   = ws + 0 * FSZ;
    float* qb   = ws + 1 * FSZ;
    float* ka   = ws + 2 * FSZ;
    float* kb   = ws + 3 * FSZ;
    float* va   = ws + 4 * FSZ;
    float* vb   = ws + 5 * FSZ;
    float* qrot = ws + 6 * FSZ;    // 4*FSZ
    float* krot = ws + 10 * FSZ;   // 4*FSZ
    float* outh = ws + 14 * FSZ;   // 4*FSZ  (total 18*FSZ = 75.5 MB)

    proj_gemm<<<dim3(128, 2, 6), 256, 0, stream>>>(q, k, v, Wqa, Wqb, Wka, Wkb, Wva, Wvb, ws);
    rot_kernel<<<dim3(QL, BS), 256, 0, stream>>>(qa, qb, qse, 0, qrot);
    rot_kernel<<<dim3(SL, BS), 256, 0, stream>>>(ka, kb, kvse, 1, krot);
    score_kernel<<<16384, 256, 0, stream>>>(qrot, krot, bias, mask, attn);
    softmax_kernel<<<16384, 256, 0, stream>>>(attn);
    pv_kernel<<<512, 256, 0, stream>>>(attn, va, vb, outh);
    oproj_kernel<<<1024, 256, 0, stream>>>(outh, Woa, Wob, outp);
}

// Round 4
// 779.997 us; speedup vs baseline: 1.3275x; 1.3275x over previous
//
#include <hip/hip_runtime.h>
#include <math.h>

#define QL 2048
#define SL 2048
#define BS 4
#define NH 4
#define FSZ ((size_t)BS * QL * 128)   // 1,048,576

typedef short bf16x8 __attribute__((ext_vector_type(8)));
typedef float f32x4 __attribute__((ext_vector_type(4)));

__device__ __forceinline__ short to_bf16_rne(float x) {
    unsigned u = __float_as_uint(x);
    unsigned r = u + 0x7fffu + ((u >> 16) & 1u);
    return (short)(r >> 16);
}

// ---------------------------------------------------------------------------
// Projection GEMM: Y[M=8192][128] = X[M][256] @ W[256][128]
// ---------------------------------------------------------------------------
__global__ __launch_bounds__(256) void proj_gemm(
    const float* __restrict__ q, const float* __restrict__ k, const float* __restrict__ v,
    const float* __restrict__ Wqa, const float* __restrict__ Wqb,
    const float* __restrict__ Wka, const float* __restrict__ Wkb,
    const float* __restrict__ Wva, const float* __restrict__ Wvb,
    float* __restrict__ ws)
{
    int id = blockIdx.z;
    const float* X; const float* W;
    const size_t HALF = (size_t)BS * QL * 256;
    switch (id) {
      case 0: X = q;        W = Wqa; break;
      case 1: X = q + HALF; W = Wqb; break;
      case 2: X = k;        W = Wka; break;
      case 3: X = k + HALF; W = Wkb; break;
      case 4: X = v;        W = Wva; break;
      default:X = v + HALF; W = Wvb; break;
    }
    float* Y = ws + (size_t)id * FSZ;
    int m0 = blockIdx.x * 64;
    int n0 = blockIdx.y * 64;
    __shared__ float At[64][68];
    __shared__ float Bt[64][68];
    int t = threadIdx.x;
    int tx = t & 15, ty = t >> 4;
    float acc[4][4] = {};
    for (int kc = 0; kc < 256; kc += 64) {
        for (int f = t; f < 1024; f += 256) {
            int row = f >> 4, c4 = (f & 15) * 4;
            *(float4*)&At[row][c4] = *(const float4*)(X + (size_t)(m0 + row) * 256 + kc + c4);
        }
        for (int f = t; f < 1024; f += 256) {
            int row = f >> 4, c4 = (f & 15) * 4;
            *(float4*)&Bt[row][c4] = *(const float4*)(W + (size_t)(kc + row) * 128 + n0 + c4);
        }
        __syncthreads();
        for (int j = 0; j < 64; j += 4) {
            float4 a4[4], b4[4];
            #pragma unroll
            for (int i = 0; i < 4; i++) a4[i] = *(const float4*)&At[ty * 4 + i][j];
            #pragma unroll
            for (int jj = 0; jj < 4; jj++) b4[jj] = *(const float4*)&Bt[j + jj][tx * 4];
            #pragma unroll
            for (int i = 0; i < 4; i++) {
                #pragma unroll
                for (int jj = 0; jj < 4; jj++) {
                    float av = ((const float*)&a4[i])[jj];
                    acc[i][0] += av * b4[jj].x;
                    acc[i][1] += av * b4[jj].y;
                    acc[i][2] += av * b4[jj].z;
                    acc[i][3] += av * b4[jj].w;
                }
            }
        }
        __syncthreads();
    }
    for (int i = 0; i < 4; i++) {
        float4 o = make_float4(acc[i][0], acc[i][1], acc[i][2], acc[i][3]);
        *(float4*)(Y + (size_t)(m0 + ty * 4 + i) * 128 + n0 + tx * 4) = o;
    }
}

// ---------------------------------------------------------------------------
// Spatial rotation (unchanged)
// ---------------------------------------------------------------------------
__global__ __launch_bounds__(256) void rot_kernel(
    const float* __restrict__ ha, const float* __restrict__ hb,
    const float* __restrict__ E0, int per_token,
    float* __restrict__ outp)
{
    int tkn = blockIdx.x;
    int b = blockIdx.y;
    const float* E = E0 + (per_token ? ((size_t)(b * SL + tkn) * 16384)
                                     : ((size_t)b * 16384));
    __shared__ float hv[4][128];
    __shared__ float outl[4][128];
    int tid = threadIdx.x;
    size_t tok = (size_t)(b * QL + tkn) * 128;
    for (int idx = tid; idx < 512; idx += 256) {
        int h = idx >> 7, d = idx & 127;
        float val = (d < 64) ? ha[tok + (h & 1) * 64 + d]
                             : hb[tok + (h >> 1) * 64 + (d - 64)];
        hv[h][d] = val;
    }
    __syncthreads();
    int w = tid >> 6, lane = tid & 63;
    int half = lane >> 5, l5 = lane & 31;
    for (int it = 0; it < 16; ++it) {
        int i = w * 32 + it * 2 + half;
        float4 e = *(const float4*)(E + (size_t)i * 128 + l5 * 4);
        float acc[4];
        #pragma unroll
        for (int h = 0; h < 4; h++) {
            float4 x = *(const float4*)&hv[h][l5 * 4];
            acc[h] = e.x * x.x + e.y * x.y + e.z * x.z + e.w * x.w;
        }
        #pragma unroll
        for (int off = 1; off < 32; off <<= 1) {
            #pragma unroll
            for (int h = 0; h < 4; h++) acc[h] += __shfl_xor(acc[h], off);
        }
        if (l5 < 4) outl[l5][i] = acc[l5];
    }
    __syncthreads();
    for (int idx = tid; idx < 512; idx += 256) {
        int h = idx >> 7, d = idx & 127;
        outp[((size_t)(b * NH + h) * QL + tkn) * 128 + d] = outl[h][d];
    }
}

// ---------------------------------------------------------------------------
// Score GEMM via split-bf16 MFMA (bf16x3):
//   S = Qrot·Krot^T * scale - 1e9*mask - bias  (raw scores into attn region)
// 128x128 tile / block, 4 waves each 64x64 (4x4 frags of 16x16x32).
// fp32 staged -> (hi,lo) bf16 planes in XOR-swizzled LDS.
// LDS row layout: 128 rows x 64 shorts; 8 slots of 8 bf16; slot = (kb*2+sel)^(row&7).
// ---------------------------------------------------------------------------
__global__ __launch_bounds__(256) void score_mfma_kernel(
    const float* __restrict__ qrot, const float* __restrict__ krot,
    const float* __restrict__ bias, const int* __restrict__ mask,
    float* __restrict__ attn)
{
    __shared__ short lA[128 * 64];
    __shared__ short lB[128 * 64];

    int bid = blockIdx.x;                       // 4096
    int wg = (bid & 7) * 512 + (bid >> 3);      // XCD-chunked swizzle (4096 % 8 == 0)
    int bh = wg >> 8;
    int qt = (wg >> 4) & 15, st = wg & 15;
    int q0 = qt * 128, s0 = st * 128;
    int b = bh >> 2;

    const float* Ag = qrot + ((size_t)bh * QL + q0) * 128;
    const float* Bg = krot + ((size_t)bh * SL + s0) * 128;

    int t = threadIdx.x;
    int srow = t >> 1, shalf = t & 1;           // staging: row 0..127, half 0/1
    int l = t & 63, w = t >> 6;
    int wr = w >> 1, wc = w & 1;                // wave quadrant
    int lr = l & 15, kb = l >> 4;               // fragment lane decode

    f32x4 acc[4][4] = {};

    for (int kc = 0; kc < 128; kc += 32) {
        // ---- stage A and B: fp32 -> (hi,lo) bf16, swizzled LDS ----
        {
            const float* srcA = Ag + (size_t)srow * 128 + kc + shalf * 16;
            const float* srcB = Bg + (size_t)srow * 128 + kc + shalf * 16;
            float xa[16], xb[16];
            #pragma unroll
            for (int j = 0; j < 4; j++) {
                *(float4*)&xa[j * 4] = *(const float4*)(srcA + j * 4);
                *(float4*)&xb[j * 4] = *(const float4*)(srcB + j * 4);
            }
            bf16x8 aH0, aL0, aH1, aL1, bH0, bL0, bH1, bL1;
            #pragma unroll
            for (int j = 0; j < 8; j++) {
                short h = to_bf16_rne(xa[j]);
                float hf = __uint_as_float(((unsigned)(unsigned short)h) << 16);
                aH0[j] = h; aL0[j] = to_bf16_rne(xa[j] - hf);
                h = to_bf16_rne(xa[j + 8]);
                hf = __uint_as_float(((unsigned)(unsigned short)h) << 16);
                aH1[j] = h; aL1[j] = to_bf16_rne(xa[j + 8] - hf);
                h = to_bf16_rne(xb[j]);
                hf = __uint_as_float(((unsigned)(unsigned short)h) << 16);
                bH0[j] = h; bL0[j] = to_bf16_rne(xb[j] - hf);
                h = to_bf16_rne(xb[j + 8]);
                hf = __uint_as_float(((unsigned)(unsigned short)h) << 16);
                bH1[j] = h; bL1[j] = to_bf16_rne(xb[j + 8] - hf);
            }
            int base = srow * 64, r7 = srow & 7;
            *(bf16x8*)&lA[base + (((4 * shalf + 0) ^ r7) * 8)] = aH0;
            *(bf16x8*)&lA[base + (((4 * shalf + 1) ^ r7) * 8)] = aL0;
            *(bf16x8*)&lA[base + (((4 * shalf + 2) ^ r7) * 8)] = aH1;
            *(bf16x8*)&lA[base + (((4 * shalf + 3) ^ r7) * 8)] = aL1;
            *(bf16x8*)&lB[base + (((4 * shalf + 0) ^ r7) * 8)] = bH0;
            *(bf16x8*)&lB[base + (((4 * shalf + 1) ^ r7) * 8)] = bL0;
            *(bf16x8*)&lB[base + (((4 * shalf + 2) ^ r7) * 8)] = bH1;
            *(bf16x8*)&lB[base + (((4 * shalf + 3) ^ r7) * 8)] = bL1;
        }
        __syncthreads();

        // ---- fragments + MFMA ----
        bf16x8 ah[4], al[4], bhv[4], blv[4];
        #pragma unroll
        for (int m = 0; m < 4; m++) {
            int r = wr * 64 + m * 16 + lr;
            int r7 = r & 7, base = r * 64;
            ah[m] = *(bf16x8*)&lA[base + (((2 * kb + 0) ^ r7) * 8)];
            al[m] = *(bf16x8*)&lA[base + (((2 * kb + 1) ^ r7) * 8)];
        }
        #pragma unroll
        for (int n = 0; n < 4; n++) {
            int r = wc * 64 + n * 16 + lr;
            int r7 = r & 7, base = r * 64;
            bhv[n] = *(bf16x8*)&lB[base + (((2 * kb + 0) ^ r7) * 8)];
            blv[n] = *(bf16x8*)&lB[base + (((2 * kb + 1) ^ r7) * 8)];
        }
        #pragma unroll
        for (int m = 0; m < 4; m++) {
            #pragma unroll
            for (int n = 0; n < 4; n++) {
                acc[m][n] = __builtin_amdgcn_mfma_f32_16x16x32_bf16(ah[m], bhv[n], acc[m][n], 0, 0, 0);
                acc[m][n] = __builtin_amdgcn_mfma_f32_16x16x32_bf16(ah[m], blv[n], acc[m][n], 0, 0, 0);
                acc[m][n] = __builtin_amdgcn_mfma_f32_16x16x32_bf16(al[m], bhv[n], acc[m][n], 0, 0, 0);
            }
        }
        __syncthreads();
    }

    // ---- epilogue: scale + mask/bias adjust, scatter to attn ----
    const float scale = 0.08838834764831845f;   // 1/sqrt(128)
    #pragma unroll
    for (int n = 0; n < 4; n++) {
        int gs = s0 + wc * 64 + n * 16 + lr;
        float adj = -1e9f * (float)mask[b * SL + gs] - bias[b * SL + gs];
        #pragma unroll
        for (int m = 0; m < 4; m++) {
            int gq = q0 + wr * 64 + m * 16 + kb * 4;   // C/D: row=(lane>>4)*4+i, col=lane&15
            float* dst = attn + ((size_t)bh * QL + gq) * SL + gs;
            f32x4 c = acc[m][n];
            dst[0 * SL] = c[0] * scale + adj;
            dst[1 * SL] = c[1] * scale + adj;
            dst[2 * SL] = c[2] * scale + adj;
            dst[3 * SL] = c[3] * scale + adj;
        }
    }
}

// ---------------------------------------------------------------------------
// Row softmax (unchanged)
// ---------------------------------------------------------------------------
__global__ __launch_bounds__(256) void softmax_kernel(float* __restrict__ attn)
{
    int blk = blockIdx.x;                       // 16384 blocks, 2 rows each
    size_t rowbase = (size_t)blk * 2 * SL;
    __shared__ float rowe[2][2048];
    __shared__ float redM[2][2];
    __shared__ float redS[2][2];
    __shared__ float linv[2];
    int t = threadIdx.x;
    for (int f = t; f < 1024; f += 256) {
        int r = f >> 9, c4 = (f & 511) * 4;
        *(float4*)&rowe[r][c4] = *(const float4*)(attn + rowbase + (size_t)r * SL + c4);
    }
    __syncthreads();
    int r = t >> 7, tr = t & 127;
    float m = -INFINITY;
    for (int kk = 0; kk < 16; ++kk) m = fmaxf(m, rowe[r][tr + 128 * kk]);
    #pragma unroll
    for (int off = 1; off < 64; off <<= 1) m = fmaxf(m, __shfl_xor(m, off));
    if ((t & 63) == 0) redM[r][(t >> 6) & 1] = m;
    __syncthreads();
    m = fmaxf(redM[r][0], redM[r][1]);
    float s = 0.f;
    for (int kk = 0; kk < 16; ++kk) {
        float e = __expf(rowe[r][tr + 128 * kk] - m);
        rowe[r][tr + 128 * kk] = e;
        s += e;
    }
    #pragma unroll
    for (int off = 1; off < 64; off <<= 1) s += __shfl_xor(s, off);
    if ((t & 63) == 0) redS[r][(t >> 6) & 1] = s;
    __syncthreads();
    if (t < 2) linv[t] = 1.0f / (redS[t][0] + redS[t][1]);
    __syncthreads();
    for (int f = t; f < 1024; f += 256) {
        int rr = f >> 9, c4 = (f & 511) * 4;
        float4 e4 = *(const float4*)&rowe[rr][c4];
        float iv = linv[rr];
        e4.x *= iv; e4.y *= iv; e4.z *= iv; e4.w *= iv;
        *(float4*)(attn + rowbase + (size_t)rr * SL + c4) = e4;
    }
}

// ---------------------------------------------------------------------------
// PV GEMM (unchanged)
// ---------------------------------------------------------------------------
__global__ __launch_bounds__(256) void pv_kernel(
    const float* __restrict__ attn, const float* __restrict__ va, const float* __restrict__ vb,
    float* __restrict__ outh)
{
    int bid = blockIdx.x;                 // 512 = 16 bh * 32 q-tiles
    int bh = bid >> 5, qt = bid & 31;
    int b = bh >> 2, h = bh & 3;
    int q0 = qt * 64;
    __shared__ float At[64][68];
    __shared__ float Bt[64][132];
    int t = threadIdx.x;
    int tx = t & 15, ty = t >> 4;
    float acc[4][8] = {};
    int hao = (h & 1) * 64, hbo = (h >> 1) * 64;
    for (int s0 = 0; s0 < SL; s0 += 64) {
        for (int f = t; f < 1024; f += 256) {
            int row = f >> 4, c4 = (f & 15) * 4;
            *(float4*)&At[row][c4] =
                *(const float4*)(attn + ((size_t)bh * QL + q0 + row) * SL + s0 + c4);
        }
        for (int f = t; f < 2048; f += 256) {
            int row = f >> 5, c4 = (f & 31) * 4;
            size_t tokoff = (size_t)(b * SL + s0 + row) * 128;
            float4 vv = (c4 < 64) ? *(const float4*)(va + tokoff + hao + c4)
                                  : *(const float4*)(vb + tokoff + hbo + (c4 - 64));
            *(float4*)&Bt[row][c4] = vv;
        }
        __syncthreads();
        for (int j = 0; j < 64; j += 4) {
            float4 a4[4];
            #pragma unroll
            for (int i = 0; i < 4; i++) a4[i] = *(const float4*)&At[ty * 4 + i][j];
            #pragma unroll
            for (int jj = 0; jj < 4; jj++) {
                float4 blo = *(const float4*)&Bt[j + jj][tx * 8];
                float4 bhi = *(const float4*)&Bt[j + jj][tx * 8 + 4];
                #pragma unroll
                for (int i = 0; i < 4; i++) {
                    float av = ((const float*)&a4[i])[jj];
                    acc[i][0] += av * blo.x; acc[i][1] += av * blo.y;
                    acc[i][2] += av * blo.z; acc[i][3] += av * blo.w;
                    acc[i][4] += av * bhi.x; acc[i][5] += av * bhi.y;
                    acc[i][6] += av * bhi.z; acc[i][7] += av * bhi.w;
                }
            }
        }
        __syncthreads();
    }
    for (int i = 0; i < 4; i++) {
        float4 o1 = make_float4(acc[i][0], acc[i][1], acc[i][2], acc[i][3]);
        float4 o2 = make_float4(acc[i][4], acc[i][5], acc[i][6], acc[i][7]);
        size_t base = ((size_t)bh * QL + q0 + ty * 4 + i) * 128 + tx * 8;
        *(float4*)(outh + base) = o1;
        *(float4*)(outh + base + 4) = o2;
    }
}

// ---------------------------------------------------------------------------
// Output projection (unchanged)
// ---------------------------------------------------------------------------
__global__ __launch_bounds__(256) void oproj_kernel(
    const float* __restrict__ outh, const float* __restrict__ Woa, const float* __restrict__ Wob,
    float* __restrict__ outp)
{
    int bid = blockIdx.x;                 // 1024
    int sel = bid >> 9;
    int rem = bid & 511;
    int b = rem >> 7;
    int rem2 = rem & 127;
    int tt = rem2 >> 2, ot = rem2 & 3;
    int t0 = tt * 64, o0 = ot * 64;
    const float* W = sel ? Wob : Woa;
    int doff = sel ? 64 : 0;
    __shared__ float At[64][68];
    __shared__ float Bt[64][68];
    int t = threadIdx.x;
    int tx = t & 15, ty = t >> 4;
    float acc[4][4] = {};
    for (int kc = 0; kc < 256; kc += 64) {
        int h = kc >> 6;
        for (int f = t; f < 1024; f += 256) {
            int row = f >> 4, c4 = (f & 15) * 4;
            *(float4*)&At[row][c4] =
                *(const float4*)(outh + ((size_t)(b * NH + h) * QL + t0 + row) * 128 + doff + c4);
        }
        for (int f = t; f < 1024; f += 256) {
            int row = f >> 4, c4 = (f & 15) * 4;
            *(float4*)&Bt[row][c4] = *(const float4*)(W + (size_t)(kc + row) * 256 + o0 + c4);
        }
        __syncthreads();
        for (int j = 0; j < 64; j += 4) {
            float4 a4[4], b4[4];
            #pragma unroll
            for (int i = 0; i < 4; i++) a4[i] = *(const float4*)&At[ty * 4 + i][j];
            #pragma unroll
            for (int jj = 0; jj < 4; jj++) b4[jj] = *(const float4*)&Bt[j + jj][tx * 4];
            #pragma unroll
            for (int i = 0; i < 4; i++) {
                #pragma unroll
                for (int jj = 0; jj < 4; jj++) {
                    float av = ((const float*)&a4[i])[jj];
                    acc[i][0] += av * b4[jj].x;
                    acc[i][1] += av * b4[jj].y;
                    acc[i][2] += av * b4[jj].z;
                    acc[i][3] += av * b4[jj].w;
                }
            }
        }
        __syncthreads();
    }
    for (int i = 0; i < 4; i++) {
        float4 o = make_float4(acc[i][0], acc[i][1], acc[i][2], acc[i][3]);
        *(float4*)(outp + ((size_t)((sel * BS + b) * QL) + t0 + ty * 4 + i) * 256 + o0 + tx * 4) = o;
    }
}

extern "C" void kernel_launch(void* const* d_in, const int* in_sizes, int n_in,
                              void* d_out, int out_size, void* d_ws, size_t ws_size,
                              hipStream_t stream)
{
    const float* q    = (const float*)d_in[0];
    const float* k    = (const float*)d_in[1];
    const float* v    = (const float*)d_in[2];
    const float* qse  = (const float*)d_in[3];
    const float* kvse = (const float*)d_in[4];
    const float* bias = (const float*)d_in[5];
    const int*   mask = (const int*)d_in[6];
    const float* Wqa  = (const float*)d_in[7];
    const float* Wqb  = (const float*)d_in[8];
    const float* Wka  = (const float*)d_in[9];
    const float* Wkb  = (const float*)d_in[10];
    const float* Wva  = (const float*)d_in[11];
    const float* Wvb  = (const float*)d_in[12];
    const float* Woa  = (const float*)d_in[13];
    const float* Wob  = (const float*)d_in[14];

    float* outp = (float*)d_out;
    float* attn = outp + (size_t)2 * BS * QL * 256;   // attn region of d_out

    float* ws   = (float*)d_ws;
    float* qa   = ws + 0 * FSZ;
    float* qb   = ws + 1 * FSZ;
    float* ka   = ws + 2 * FSZ;
    float* kb   = ws + 3 * FSZ;
    float* va   = ws + 4 * FSZ;
    float* vb   = ws + 5 * FSZ;
    float* qrot = ws + 6 * FSZ;    // 4*FSZ
    float* krot = ws + 10 * FSZ;   // 4*FSZ
    float* outh = ws + 14 * FSZ;   // 4*FSZ

    proj_gemm<<<dim3(128, 2, 6), 256, 0, stream>>>(q, k, v, Wqa, Wqb, Wka, Wkb, Wva, Wvb, ws);
    rot_kernel<<<dim3(QL, BS), 256, 0, stream>>>(qa, qb, qse, 0, qrot);
    rot_kernel<<<dim3(SL, BS), 256, 0, stream>>>(ka, kb, kvse, 1, krot);
    score_mfma_kernel<<<4096, 256, 0, stream>>>(qrot, krot, bias, mask, attn);
    softmax_kernel<<<16384, 256, 0, stream>>>(attn);
    pv_kernel<<<512, 256, 0, stream>>>(attn, va, vb, outh);
    oproj_kernel<<<1024, 256, 0, stream>>>(outh, Woa, Wob, outp);
}

// Round 5
// 673.935 us; speedup vs baseline: 1.5364x; 1.1574x over previous
//
#include <hip/hip_runtime.h>
#include <math.h>

#define QL 2048
#define SL 2048
#define BS 4
#define NH 4
#define FSZ ((size_t)BS * QL * 128)   // 1,048,576

typedef short bf16x8 __attribute__((ext_vector_type(8)));
typedef float f32x4 __attribute__((ext_vector_type(4)));

__device__ __forceinline__ short to_bf16_rne(float x) {
    unsigned u = __float_as_uint(x);
    unsigned r = u + 0x7fffu + ((u >> 16) & 1u);
    return (short)(r >> 16);
}

// ---------------------------------------------------------------------------
// Projection GEMM: Y[M=8192][128] = X[M][256] @ W[256][128]
// ---------------------------------------------------------------------------
__global__ __launch_bounds__(256) void proj_gemm(
    const float* __restrict__ q, const float* __restrict__ k, const float* __restrict__ v,
    const float* __restrict__ Wqa, const float* __restrict__ Wqb,
    const float* __restrict__ Wka, const float* __restrict__ Wkb,
    const float* __restrict__ Wva, const float* __restrict__ Wvb,
    float* __restrict__ ws)
{
    int id = blockIdx.z;
    const float* X; const float* W;
    const size_t HALF = (size_t)BS * QL * 256;
    switch (id) {
      case 0: X = q;        W = Wqa; break;
      case 1: X = q + HALF; W = Wqb; break;
      case 2: X = k;        W = Wka; break;
      case 3: X = k + HALF; W = Wkb; break;
      case 4: X = v;        W = Wva; break;
      default:X = v + HALF; W = Wvb; break;
    }
    float* Y = ws + (size_t)id * FSZ;
    int m0 = blockIdx.x * 64;
    int n0 = blockIdx.y * 64;
    __shared__ float At[64][68];
    __shared__ float Bt[64][68];
    int t = threadIdx.x;
    int tx = t & 15, ty = t >> 4;
    float acc[4][4] = {};
    for (int kc = 0; kc < 256; kc += 64) {
        for (int f = t; f < 1024; f += 256) {
            int row = f >> 4, c4 = (f & 15) * 4;
            *(float4*)&At[row][c4] = *(const float4*)(X + (size_t)(m0 + row) * 256 + kc + c4);
        }
        for (int f = t; f < 1024; f += 256) {
            int row = f >> 4, c4 = (f & 15) * 4;
            *(float4*)&Bt[row][c4] = *(const float4*)(W + (size_t)(kc + row) * 128 + n0 + c4);
        }
        __syncthreads();
        for (int j = 0; j < 64; j += 4) {
            float4 a4[4], b4[4];
            #pragma unroll
            for (int i = 0; i < 4; i++) a4[i] = *(const float4*)&At[ty * 4 + i][j];
            #pragma unroll
            for (int jj = 0; jj < 4; jj++) b4[jj] = *(const float4*)&Bt[j + jj][tx * 4];
            #pragma unroll
            for (int i = 0; i < 4; i++) {
                #pragma unroll
                for (int jj = 0; jj < 4; jj++) {
                    float av = ((const float*)&a4[i])[jj];
                    acc[i][0] += av * b4[jj].x;
                    acc[i][1] += av * b4[jj].y;
                    acc[i][2] += av * b4[jj].z;
                    acc[i][3] += av * b4[jj].w;
                }
            }
        }
        __syncthreads();
    }
    for (int i = 0; i < 4; i++) {
        float4 o = make_float4(acc[i][0], acc[i][1], acc[i][2], acc[i][3]);
        *(float4*)(Y + (size_t)(m0 + ty * 4 + i) * 128 + n0 + tx * 4) = o;
    }
}

// ---------------------------------------------------------------------------
// Spatial rotation (unchanged)
// ---------------------------------------------------------------------------
__global__ __launch_bounds__(256) void rot_kernel(
    const float* __restrict__ ha, const float* __restrict__ hb,
    const float* __restrict__ E0, int per_token,
    float* __restrict__ outp)
{
    int tkn = blockIdx.x;
    int b = blockIdx.y;
    const float* E = E0 + (per_token ? ((size_t)(b * SL + tkn) * 16384)
                                     : ((size_t)b * 16384));
    __shared__ float hv[4][128];
    __shared__ float outl[4][128];
    int tid = threadIdx.x;
    size_t tok = (size_t)(b * QL + tkn) * 128;
    for (int idx = tid; idx < 512; idx += 256) {
        int h = idx >> 7, d = idx & 127;
        float val = (d < 64) ? ha[tok + (h & 1) * 64 + d]
                             : hb[tok + (h >> 1) * 64 + (d - 64)];
        hv[h][d] = val;
    }
    __syncthreads();
    int w = tid >> 6, lane = tid & 63;
    int half = lane >> 5, l5 = lane & 31;
    for (int it = 0; it < 16; ++it) {
        int i = w * 32 + it * 2 + half;
        float4 e = *(const float4*)(E + (size_t)i * 128 + l5 * 4);
        float acc[4];
        #pragma unroll
        for (int h = 0; h < 4; h++) {
            float4 x = *(const float4*)&hv[h][l5 * 4];
            acc[h] = e.x * x.x + e.y * x.y + e.z * x.z + e.w * x.w;
        }
        #pragma unroll
        for (int off = 1; off < 32; off <<= 1) {
            #pragma unroll
            for (int h = 0; h < 4; h++) acc[h] += __shfl_xor(acc[h], off);
        }
        if (l5 < 4) outl[l5][i] = acc[l5];
    }
    __syncthreads();
    for (int idx = tid; idx < 512; idx += 256) {
        int h = idx >> 7, d = idx & 127;
        outp[((size_t)(b * NH + h) * QL + tkn) * 128 + d] = outl[h][d];
    }
}

// ---------------------------------------------------------------------------
// Score GEMM via split-bf16 MFMA (validated round 4, unchanged)
// ---------------------------------------------------------------------------
__global__ __launch_bounds__(256) void score_mfma_kernel(
    const float* __restrict__ qrot, const float* __restrict__ krot,
    const float* __restrict__ bias, const int* __restrict__ mask,
    float* __restrict__ attn)
{
    __shared__ short lA[128 * 64];
    __shared__ short lB[128 * 64];

    int bid = blockIdx.x;                       // 4096
    int wg = (bid & 7) * 512 + (bid >> 3);      // XCD-chunked swizzle
    int bh = wg >> 8;
    int qt = (wg >> 4) & 15, st = wg & 15;
    int q0 = qt * 128, s0 = st * 128;
    int b = bh >> 2;

    const float* Ag = qrot + ((size_t)bh * QL + q0) * 128;
    const float* Bg = krot + ((size_t)bh * SL + s0) * 128;

    int t = threadIdx.x;
    int srow = t >> 1, shalf = t & 1;
    int l = t & 63, w = t >> 6;
    int wr = w >> 1, wc = w & 1;
    int lr = l & 15, kb = l >> 4;

    f32x4 acc[4][4] = {};

    for (int kc = 0; kc < 128; kc += 32) {
        {
            const float* srcA = Ag + (size_t)srow * 128 + kc + shalf * 16;
            const float* srcB = Bg + (size_t)srow * 128 + kc + shalf * 16;
            float xa[16], xb[16];
            #pragma unroll
            for (int j = 0; j < 4; j++) {
                *(float4*)&xa[j * 4] = *(const float4*)(srcA + j * 4);
                *(float4*)&xb[j * 4] = *(const float4*)(srcB + j * 4);
            }
            bf16x8 aH0, aL0, aH1, aL1, bH0, bL0, bH1, bL1;
            #pragma unroll
            for (int j = 0; j < 8; j++) {
                short h = to_bf16_rne(xa[j]);
                float hf = __uint_as_float(((unsigned)(unsigned short)h) << 16);
                aH0[j] = h; aL0[j] = to_bf16_rne(xa[j] - hf);
                h = to_bf16_rne(xa[j + 8]);
                hf = __uint_as_float(((unsigned)(unsigned short)h) << 16);
                aH1[j] = h; aL1[j] = to_bf16_rne(xa[j + 8] - hf);
                h = to_bf16_rne(xb[j]);
                hf = __uint_as_float(((unsigned)(unsigned short)h) << 16);
                bH0[j] = h; bL0[j] = to_bf16_rne(xb[j] - hf);
                h = to_bf16_rne(xb[j + 8]);
                hf = __uint_as_float(((unsigned)(unsigned short)h) << 16);
                bH1[j] = h; bL1[j] = to_bf16_rne(xb[j + 8] - hf);
            }
            int base = srow * 64, r7 = srow & 7;
            *(bf16x8*)&lA[base + (((4 * shalf + 0) ^ r7) * 8)] = aH0;
            *(bf16x8*)&lA[base + (((4 * shalf + 1) ^ r7) * 8)] = aL0;
            *(bf16x8*)&lA[base + (((4 * shalf + 2) ^ r7) * 8)] = aH1;
            *(bf16x8*)&lA[base + (((4 * shalf + 3) ^ r7) * 8)] = aL1;
            *(bf16x8*)&lB[base + (((4 * shalf + 0) ^ r7) * 8)] = bH0;
            *(bf16x8*)&lB[base + (((4 * shalf + 1) ^ r7) * 8)] = bL0;
            *(bf16x8*)&lB[base + (((4 * shalf + 2) ^ r7) * 8)] = bH1;
            *(bf16x8*)&lB[base + (((4 * shalf + 3) ^ r7) * 8)] = bL1;
        }
        __syncthreads();

        bf16x8 ah[4], al[4], bhv[4], blv[4];
        #pragma unroll
        for (int m = 0; m < 4; m++) {
            int r = wr * 64 + m * 16 + lr;
            int r7 = r & 7, base = r * 64;
            ah[m] = *(bf16x8*)&lA[base + (((2 * kb + 0) ^ r7) * 8)];
            al[m] = *(bf16x8*)&lA[base + (((2 * kb + 1) ^ r7) * 8)];
        }
        #pragma unroll
        for (int n = 0; n < 4; n++) {
            int r = wc * 64 + n * 16 + lr;
            int r7 = r & 7, base = r * 64;
            bhv[n] = *(bf16x8*)&lB[base + (((2 * kb + 0) ^ r7) * 8)];
            blv[n] = *(bf16x8*)&lB[base + (((2 * kb + 1) ^ r7) * 8)];
        }
        #pragma unroll
        for (int m = 0; m < 4; m++) {
            #pragma unroll
            for (int n = 0; n < 4; n++) {
                acc[m][n] = __builtin_amdgcn_mfma_f32_16x16x32_bf16(ah[m], bhv[n], acc[m][n], 0, 0, 0);
                acc[m][n] = __builtin_amdgcn_mfma_f32_16x16x32_bf16(ah[m], blv[n], acc[m][n], 0, 0, 0);
                acc[m][n] = __builtin_amdgcn_mfma_f32_16x16x32_bf16(al[m], bhv[n], acc[m][n], 0, 0, 0);
            }
        }
        __syncthreads();
    }

    const float scale = 0.08838834764831845f;   // 1/sqrt(128)
    #pragma unroll
    for (int n = 0; n < 4; n++) {
        int gs = s0 + wc * 64 + n * 16 + lr;
        float adj = -1e9f * (float)mask[b * SL + gs] - bias[b * SL + gs];
        #pragma unroll
        for (int m = 0; m < 4; m++) {
            int gq = q0 + wr * 64 + m * 16 + kb * 4;
            float* dst = attn + ((size_t)bh * QL + gq) * SL + gs;
            f32x4 c = acc[m][n];
            dst[0 * SL] = c[0] * scale + adj;
            dst[1 * SL] = c[1] * scale + adj;
            dst[2 * SL] = c[2] * scale + adj;
            dst[3 * SL] = c[3] * scale + adj;
        }
    }
}

// ---------------------------------------------------------------------------
// Row softmax (unchanged)
// ---------------------------------------------------------------------------
__global__ __launch_bounds__(256) void softmax_kernel(float* __restrict__ attn)
{
    int blk = blockIdx.x;                       // 16384 blocks, 2 rows each
    size_t rowbase = (size_t)blk * 2 * SL;
    __shared__ float rowe[2][2048];
    __shared__ float redM[2][2];
    __shared__ float redS[2][2];
    __shared__ float linv[2];
    int t = threadIdx.x;
    for (int f = t; f < 1024; f += 256) {
        int r = f >> 9, c4 = (f & 511) * 4;
        *(float4*)&rowe[r][c4] = *(const float4*)(attn + rowbase + (size_t)r * SL + c4);
    }
    __syncthreads();
    int r = t >> 7, tr = t & 127;
    float m = -INFINITY;
    for (int kk = 0; kk < 16; ++kk) m = fmaxf(m, rowe[r][tr + 128 * kk]);
    #pragma unroll
    for (int off = 1; off < 64; off <<= 1) m = fmaxf(m, __shfl_xor(m, off));
    if ((t & 63) == 0) redM[r][(t >> 6) & 1] = m;
    __syncthreads();
    m = fmaxf(redM[r][0], redM[r][1]);
    float s = 0.f;
    for (int kk = 0; kk < 16; ++kk) {
        float e = __expf(rowe[r][tr + 128 * kk] - m);
        rowe[r][tr + 128 * kk] = e;
        s += e;
    }
    #pragma unroll
    for (int off = 1; off < 64; off <<= 1) s += __shfl_xor(s, off);
    if ((t & 63) == 0) redS[r][(t >> 6) & 1] = s;
    __syncthreads();
    if (t < 2) linv[t] = 1.0f / (redS[t][0] + redS[t][1]);
    __syncthreads();
    for (int f = t; f < 1024; f += 256) {
        int rr = f >> 9, c4 = (f & 511) * 4;
        float4 e4 = *(const float4*)&rowe[rr][c4];
        float iv = linv[rr];
        e4.x *= iv; e4.y *= iv; e4.z *= iv; e4.w *= iv;
        *(float4*)(attn + rowbase + (size_t)rr * SL + c4) = e4;
    }
}

// ---------------------------------------------------------------------------
// V pre-transpose: vT[bh][sblk][d][64 shorts] in PV's swizzled LDS byte order.
// slot = (2*kb + sel) ^ (d&7), content = split-bf16 of Vh[sblk*32+kb*8+j][d].
// ---------------------------------------------------------------------------
__global__ __launch_bounds__(256) void vtrans_kernel(
    const float* __restrict__ va, const float* __restrict__ vb,
    short* __restrict__ vT)
{
    int sblk = blockIdx.x;                    // 64
    int bh = blockIdx.y;                      // 16
    int b = bh >> 2, h = bh & 3;
    int hao = (h & 1) * 64, hbo = (h >> 1) * 64;
    __shared__ float vt[32][132];
    int t = threadIdx.x;
    for (int f = t; f < 1024; f += 256) {
        int s = f >> 5, c4 = (f & 31) * 4;
        size_t tok = (size_t)(b * SL + sblk * 32 + s) * 128;
        float4 vv = (c4 < 64) ? *(const float4*)(va + tok + hao + c4)
                              : *(const float4*)(vb + tok + hbo + (c4 - 64));
        *(float4*)&vt[s][c4] = vv;
    }
    __syncthreads();
    int d = t >> 1, shalf = t & 1;            // shalf covers kb = 2*shalf .. +1
    bf16x8 hi[2], lo[2];
    #pragma unroll
    for (int kb2 = 0; kb2 < 2; kb2++) {
        int kb = shalf * 2 + kb2;
        #pragma unroll
        for (int j = 0; j < 8; j++) {
            float x = vt[kb * 8 + j][d];
            short hh = to_bf16_rne(x);
            float hf = __uint_as_float(((unsigned)(unsigned short)hh) << 16);
            hi[kb2][j] = hh;
            lo[kb2][j] = to_bf16_rne(x - hf);
        }
    }
    size_t base = (((size_t)bh * 64 + sblk) * 128 + d) * 64;
    int d7 = d & 7;
    *(bf16x8*)&vT[base + (size_t)(((2 * (shalf * 2 + 0) + 0) ^ d7) * 8)] = hi[0];
    *(bf16x8*)&vT[base + (size_t)(((2 * (shalf * 2 + 0) + 1) ^ d7) * 8)] = lo[0];
    *(bf16x8*)&vT[base + (size_t)(((2 * (shalf * 2 + 1) + 0) ^ d7) * 8)] = hi[1];
    *(bf16x8*)&vT[base + (size_t)(((2 * (shalf * 2 + 1) + 1) ^ d7) * 8)] = lo[1];
}

// ---------------------------------------------------------------------------
// PV GEMM via split-bf16 MFMA: outh[bh,q,d] = sum_s P[q,s]*Vh[s,d]
// 128q x 128d tile / block, K-step 32 s. A = P (fp32->split on stage),
// B = pre-transposed V (linear copy of pre-swizzled bytes).
// ---------------------------------------------------------------------------
__global__ __launch_bounds__(256) void pv_mfma_kernel(
    const float* __restrict__ attn, const short* __restrict__ vT,
    float* __restrict__ outh)
{
    __shared__ short lA[128 * 64];
    __shared__ short lB[128 * 64];

    int bid = blockIdx.x;                     // 256
    int wg = (bid & 7) * 32 + (bid >> 3);     // XCD swizzle (256 % 8 == 0)
    int bh = wg >> 4, qt = wg & 15;
    int q0 = qt * 128;

    const float* Ag = attn + ((size_t)bh * QL + q0) * SL;
    const short* Bg = vT + (size_t)bh * 64 * 8192;

    int t = threadIdx.x;
    int srow = t >> 1, shalf = t & 1;
    int l = t & 63, w = t >> 6;
    int wr = w >> 1, wc = w & 1;
    int lr = l & 15, kb = l >> 4;

    f32x4 acc[4][4] = {};

    for (int sblk = 0; sblk < 64; sblk++) {
        // stage A: P rows fp32 -> (hi,lo), swizzled
        {
            const float* src = Ag + (size_t)srow * SL + sblk * 32 + shalf * 16;
            float x[16];
            #pragma unroll
            for (int j = 0; j < 4; j++)
                *(float4*)&x[j * 4] = *(const float4*)(src + j * 4);
            bf16x8 h0, l0, h1, l1;
            #pragma unroll
            for (int j = 0; j < 8; j++) {
                short hh = to_bf16_rne(x[j]);
                float hf = __uint_as_float(((unsigned)(unsigned short)hh) << 16);
                h0[j] = hh; l0[j] = to_bf16_rne(x[j] - hf);
                hh = to_bf16_rne(x[j + 8]);
                hf = __uint_as_float(((unsigned)(unsigned short)hh) << 16);
                h1[j] = hh; l1[j] = to_bf16_rne(x[j + 8] - hf);
            }
            int base = srow * 64, r7 = srow & 7;
            *(bf16x8*)&lA[base + (((4 * shalf + 0) ^ r7) * 8)] = h0;
            *(bf16x8*)&lA[base + (((4 * shalf + 1) ^ r7) * 8)] = l0;
            *(bf16x8*)&lA[base + (((4 * shalf + 2) ^ r7) * 8)] = h1;
            *(bf16x8*)&lA[base + (((4 * shalf + 3) ^ r7) * 8)] = l1;
        }
        // stage B: linear 16 KB copy of pre-swizzled bytes
        {
            const bf16x8* src = (const bf16x8*)(Bg + (size_t)sblk * 8192) + t * 4;
            bf16x8 v0 = src[0], v1 = src[1], v2 = src[2], v3 = src[3];
            bf16x8* dst = (bf16x8*)lB + t * 4;
            dst[0] = v0; dst[1] = v1; dst[2] = v2; dst[3] = v3;
        }
        __syncthreads();

        bf16x8 ah[4], al[4], bhv[4], blv[4];
        #pragma unroll
        for (int m = 0; m < 4; m++) {
            int r = wr * 64 + m * 16 + lr;
            int r7 = r & 7, base = r * 64;
            ah[m] = *(bf16x8*)&lA[base + (((2 * kb + 0) ^ r7) * 8)];
            al[m] = *(bf16x8*)&lA[base + (((2 * kb + 1) ^ r7) * 8)];
        }
        #pragma unroll
        for (int n = 0; n < 4; n++) {
            int r = wc * 64 + n * 16 + lr;
            int r7 = r & 7, base = r * 64;
            bhv[n] = *(bf16x8*)&lB[base + (((2 * kb + 0) ^ r7) * 8)];
            blv[n] = *(bf16x8*)&lB[base + (((2 * kb + 1) ^ r7) * 8)];
        }
        #pragma unroll
        for (int m = 0; m < 4; m++) {
            #pragma unroll
            for (int n = 0; n < 4; n++) {
                acc[m][n] = __builtin_amdgcn_mfma_f32_16x16x32_bf16(ah[m], bhv[n], acc[m][n], 0, 0, 0);
                acc[m][n] = __builtin_amdgcn_mfma_f32_16x16x32_bf16(ah[m], blv[n], acc[m][n], 0, 0, 0);
                acc[m][n] = __builtin_amdgcn_mfma_f32_16x16x32_bf16(al[m], bhv[n], acc[m][n], 0, 0, 0);
            }
        }
        __syncthreads();
    }

    #pragma unroll
    for (int n = 0; n < 4; n++) {
        int gd = wc * 64 + n * 16 + lr;
        #pragma unroll
        for (int m = 0; m < 4; m++) {
            int gq = q0 + wr * 64 + m * 16 + kb * 4;
            float* dst = outh + ((size_t)bh * QL + gq) * 128 + gd;
            f32x4 c = acc[m][n];
            dst[0 * 128] = c[0];
            dst[1 * 128] = c[1];
            dst[2 * 128] = c[2];
            dst[3 * 128] = c[3];
        }
    }
}

// ---------------------------------------------------------------------------
// Output projection (unchanged)
// ---------------------------------------------------------------------------
__global__ __launch_bounds__(256) void oproj_kernel(
    const float* __restrict__ outh, const float* __restrict__ Woa, const float* __restrict__ Wob,
    float* __restrict__ outp)
{
    int bid = blockIdx.x;                 // 1024
    int sel = bid >> 9;
    int rem = bid & 511;
    int b = rem >> 7;
    int rem2 = rem & 127;
    int tt = rem2 >> 2, ot = rem2 & 3;
    int t0 = tt * 64, o0 = ot * 64;
    const float* W = sel ? Wob : Woa;
    int doff = sel ? 64 : 0;
    __shared__ float At[64][68];
    __shared__ float Bt[64][68];
    int t = threadIdx.x;
    int tx = t & 15, ty = t >> 4;
    float acc[4][4] = {};
    for (int kc = 0; kc < 256; kc += 64) {
        int h = kc >> 6;
        for (int f = t; f < 1024; f += 256) {
            int row = f >> 4, c4 = (f & 15) * 4;
            *(float4*)&At[row][c4] =
                *(const float4*)(outh + ((size_t)(b * NH + h) * QL + t0 + row) * 128 + doff + c4);
        }
        for (int f = t; f < 1024; f += 256) {
            int row = f >> 4, c4 = (f & 15) * 4;
            *(float4*)&Bt[row][c4] = *(const float4*)(W + (size_t)(kc + row) * 256 + o0 + c4);
        }
        __syncthreads();
        for (int j = 0; j < 64; j += 4) {
            float4 a4[4], b4[4];
            #pragma unroll
            for (int i = 0; i < 4; i++) a4[i] = *(const float4*)&At[ty * 4 + i][j];
            #pragma unroll
            for (int jj = 0; jj < 4; jj++) b4[jj] = *(const float4*)&Bt[j + jj][tx * 4];
            #pragma unroll
            for (int i = 0; i < 4; i++) {
                #pragma unroll
                for (int jj = 0; jj < 4; jj++) {
                    float av = ((const float*)&a4[i])[jj];
                    acc[i][0] += av * b4[jj].x;
                    acc[i][1] += av * b4[jj].y;
                    acc[i][2] += av * b4[jj].z;
                    acc[i][3] += av * b4[jj].w;
                }
            }
        }
        __syncthreads();
    }
    for (int i = 0; i < 4; i++) {
        float4 o = make_float4(acc[i][0], acc[i][1], acc[i][2], acc[i][3]);
        *(float4*)(outp + ((size_t)((sel * BS + b) * QL) + t0 + ty * 4 + i) * 256 + o0 + tx * 4) = o;
    }
}

extern "C" void kernel_launch(void* const* d_in, const int* in_sizes, int n_in,
                              void* d_out, int out_size, void* d_ws, size_t ws_size,
                              hipStream_t stream)
{
    const float* q    = (const float*)d_in[0];
    const float* k    = (const float*)d_in[1];
    const float* v    = (const float*)d_in[2];
    const float* qse  = (const float*)d_in[3];
    const float* kvse = (const float*)d_in[4];
    const float* bias = (const float*)d_in[5];
    const int*   mask = (const int*)d_in[6];
    const float* Wqa  = (const float*)d_in[7];
    const float* Wqb  = (const float*)d_in[8];
    const float* Wka  = (const float*)d_in[9];
    const float* Wkb  = (const float*)d_in[10];
    const float* Wva  = (const float*)d_in[11];
    const float* Wvb  = (const float*)d_in[12];
    const float* Woa  = (const float*)d_in[13];
    const float* Wob  = (const float*)d_in[14];

    float* outp = (float*)d_out;
    float* attn = outp + (size_t)2 * BS * QL * 256;   // attn region of d_out

    float* ws   = (float*)d_ws;
    float* qa   = ws + 0 * FSZ;
    float* qb   = ws + 1 * FSZ;
    float* ka   = ws + 2 * FSZ;
    float* kb   = ws + 3 * FSZ;
    float* va   = ws + 4 * FSZ;
    float* vb   = ws + 5 * FSZ;
    float* qrot = ws + 6 * FSZ;    // 4*FSZ
    float* krot = ws + 10 * FSZ;   // 4*FSZ
    float* outh = ws + 14 * FSZ;   // 4*FSZ
    short* vT   = (short*)(ws + 18 * FSZ);   // 4*FSZ equivalent (16.8 MB)

    proj_gemm<<<dim3(128, 2, 6), 256, 0, stream>>>(q, k, v, Wqa, Wqb, Wka, Wkb, Wva, Wvb, ws);
    vtrans_kernel<<<dim3(64, 16), 256, 0, stream>>>(va, vb, vT);
    rot_kernel<<<dim3(QL, BS), 256, 0, stream>>>(qa, qb, qse, 0, qrot);
    rot_kernel<<<dim3(SL, BS), 256, 0, stream>>>(ka, kb, kvse, 1, krot);
    score_mfma_kernel<<<4096, 256, 0, stream>>>(qrot, krot, bias, mask, attn);
    softmax_kernel<<<16384, 256, 0, stream>>>(attn);
    pv_mfma_kernel<<<256, 256, 0, stream>>>(attn, vT, outh);
    oproj_kernel<<<1024, 256, 0, stream>>>(outh, Woa, Wob, outp);
}